// Round 8
// baseline (510.047 us; speedup 1.0000x reference)
//
#include <hip/hip_runtime.h>
#include <hip/hip_fp16.h>
#include <math.h>

#define NNODE 100000
#define NEDGE 1600000
#define FIN   128
#define AGG   48
#define FCH   192
#define NCLS  10
#define SLOPE 0.2f
#define L2E   1.44269504088896340736f

#define NBUCK 391     // ceil(NNODE/256) coarse dst-buckets (256 nodes each)
#define BCAP  4992    // bucket capacity: mean 4096, sigma 64 -> +14 sigma
#define EPB   2048    // edges per binA block

// fp16 pack/unpack helpers
__device__ __forceinline__ float2 h2f(int p) {
    union { int i; __half2 h; } u; u.i = p;
    return __half22float2(u.h);
}
__device__ __forceinline__ int f2h(float a, float b) {
    union { __half2 h; int i; } u;
    u.h = __floats2half2_rn(a, b);
    return u.i;
}

// ---------------- CSR build (two-level counting sort) ----------------

// Pass A, LDS-staged: bin 2048 edges into coarse buckets. Records are staged
// in LDS grouped by bucket (hist -> scan -> slot), then written out linearly
// so each bucket-run hits global memory as temporally-adjacent coalesced
// stores (full-line merges; R7 showed 3.3x write amplification from
// time-scattered 16B partials). Also builds deg[] (fused histogram).
__global__ __launch_bounds__(256) void binA_kernel(const int* __restrict__ ei,
                                                   const float4* __restrict__ ea,
                                                   int* __restrict__ deg,
                                                   int* __restrict__ bcnt,
                                                   int4* __restrict__ bbuf) {
    __shared__ int  hist[NBUCK];
    __shared__ int  lofs[NBUCK];     // exclusive scan of hist (block-local)
    __shared__ int  gbase[NBUCK];    // reserved global base within bucket
    __shared__ int  scA[512], scB[512];
    __shared__ int  gidx[EPB];       // per-slot global bbuf index (-1 = drop)
    __shared__ int4 stage[EPB];

    const int t = threadIdx.x;
    const int wgbase = blockIdx.x * EPB;
    const int nvalid = min(EPB, NEDGE - wgbase);

    for (int i = t; i < NBUCK; i += 256) hist[i] = 0;
    __syncthreads();

    int d[8], rank[8];
#pragma unroll
    for (int i = 0; i < 8; ++i) {
        int e = wgbase + i * 256 + t;
        if (e < NEDGE) {
            d[i] = ei[NEDGE + e];
            rank[i] = atomicAdd(&hist[d[i] >> 8], 1);
            atomicAdd(&deg[d[i]], 1);
        } else d[i] = -1;
    }
    __syncthreads();

    // Hillis-Steele inclusive scan of hist (padded to 512), ping-pong A->B
    {
        scA[t] = (t < NBUCK) ? hist[t] : 0;
        scA[t + 256] = (t + 256 < NBUCK) ? hist[t + 256] : 0;
        __syncthreads();
        int* src = scA; int* dst = scB;
#pragma unroll
        for (int o = 1; o < 512; o <<= 1) {
            int i0 = t, i1 = t + 256;
            int v0 = src[i0] + ((i0 >= o) ? src[i0 - o] : 0);
            int v1 = src[i1] + ((i1 >= o) ? src[i1 - o] : 0);
            __syncthreads();
            dst[i0] = v0; dst[i1] = v1;
            __syncthreads();
            int* tmp = src; src = dst; dst = tmp;
        }
        // 9 steps -> result currently in src (after final swap)
        if (t < NBUCK) lofs[t] = src[t] - hist[t];
        if (t + 256 < NBUCK) lofs[t + 256] = src[t + 256] - hist[t + 256];
    }
    // reserve global ranges (one atomic per non-empty (wg,bucket))
    for (int i = t; i < NBUCK; i += 256)
        gbase[i] = hist[i] ? atomicAdd(&bcnt[i], hist[i]) : 0;
    __syncthreads();

    // stage records grouped by bucket
#pragma unroll
    for (int i = 0; i < 8; ++i) {
        int e = wgbase + i * 256 + t;
        if (e < NEDGE) {
            int b = d[i] >> 8;
            int slot = lofs[b] + rank[i];
            int gp = gbase[b] + rank[i];
            float4 v = ea[e];
            stage[slot] = make_int4(ei[e], d[i], f2h(v.x, v.y), f2h(v.z, v.w));
            gidx[slot] = (gp < BCAP) ? (b * BCAP + gp) : -1;
        }
    }
    __syncthreads();

    // linear write-out: consecutive slots = same bucket consecutive global
    // addresses -> coalesced full-line runs
    for (int i = t; i < nvalid; i += 256) {
        int gi = gidx[i];
        if (gi >= 0) bbuf[gi] = stage[i];
    }
}

__global__ void scan1_kernel(const int* __restrict__ deg, int* __restrict__ starts,
                             int* __restrict__ bsum) {
    __shared__ int s[256];
    int t = threadIdx.x;
    int i = blockIdx.x * 256 + t;
    int v = (i < NNODE) ? deg[i] : 0;
    s[t] = v;
    __syncthreads();
    int acc = v;
    for (int o = 1; o < 256; o <<= 1) {
        int x = (t >= o) ? s[t - o] : 0;
        __syncthreads();
        acc += x;
        s[t] = acc;
        __syncthreads();
    }
    if (i < NNODE) starts[i] = acc - v;
    if (t == 255) bsum[blockIdx.x] = acc;
}

__global__ void scan2_kernel(int* __restrict__ bsum, int nb) {
    __shared__ int s[512];
    int t = threadIdx.x;
    int v = (t < nb) ? bsum[t] : 0;
    s[t] = v;
    __syncthreads();
    int acc = v;
    for (int o = 1; o < 512; o <<= 1) {
        int x = (t >= o) ? s[t - o] : 0;
        __syncthreads();
        acc += x;
        s[t] = acc;
        __syncthreads();
    }
    if (t < nb) bsum[t] = acc - v;
}

__global__ void scan3_kernel(int* __restrict__ starts, const int* __restrict__ bsum) {
    int i = blockIdx.x * 256 + threadIdx.x;
    if (i < NNODE) starts[i] += bsum[blockIdx.x];
    if (i == 0) starts[NNODE] = NEDGE;
}

// Pass B: one workgroup (1024 threads) per coarse bucket; LDS per-node
// cursors seeded from starts[]; records land in the bucket's contiguous CSR
// span (~64KB, one XCD) -> merged writes.
__global__ __launch_bounds__(1024) void binB_kernel(const int* __restrict__ bcnt,
                                                    const int4* __restrict__ bbuf,
                                                    const int* __restrict__ starts,
                                                    int4* __restrict__ edges) {
    __shared__ int lcur[256];
    const int b = blockIdx.x;
    const int t = threadIdx.x;
    if (t < 256) {
        int node = (b << 8) + t;
        lcur[t] = (node < NNODE) ? starts[node] : 0;
    }
    __syncthreads();
    int cnt = bcnt[b];
    if (cnt > BCAP) cnt = BCAP;
    for (int i = t; i < cnt; i += 1024) {
        int4 rec = bbuf[(size_t)b * BCAP + i];
        int pos = atomicAdd(&lcur[rec.y & 255], 1);
        edges[pos] = make_int4(rec.x, rec.z, rec.w, 0);
    }
}

// ---------------- per-layer kernels ----------------

// LDS-tiled dual GEMM. xl written packed fp16, row padded to 64 halfs (128B)
// so the aggregate's per-edge gather touches exactly one cache line.
template <int K>
__global__ __launch_bounds__(192) void transform_tiled(
    const float* __restrict__ h,
    const float* __restrict__ Wl, const float* __restrict__ bl,
    const float* __restrict__ Wr, const float* __restrict__ br,
    __half* __restrict__ xlh, float* __restrict__ xr)
{
    constexpr int NT = 48;
    constexpr int KP = K + 1;
    __shared__ float sWl[K * 48];
    __shared__ float sWr[K * 48];
    __shared__ float sH[NT * KP];

    const int t = threadIdx.x;
    const int base = blockIdx.x * NT;

    for (int idx = t; idx < 48 * K; idx += 192) {
        int k = idx / K;
        int j = idx - k * K;
        sWl[j * 48 + k] = Wl[idx];
        sWr[j * 48 + k] = Wr[idx];
    }
    for (int p = t; p < NT * (K / 4); p += 192) {
        int row = p / (K / 4);
        int c4  = p - row * (K / 4);
        int gn  = base + row;
        float4 v = (gn < NNODE) ? ((const float4*)h)[(size_t)gn * (K / 4) + c4]
                                : make_float4(0.f, 0.f, 0.f, 0.f);
        float* d = &sH[row * KP + c4 * 4];
        d[0] = v.x; d[1] = v.y; d[2] = v.z; d[3] = v.w;
    }
    __syncthreads();

    const int q  = t % 12;
    const int ng = t / 12;
    float al[3][4] = {};
    float ar[3][4] = {};

    const float4* sWl4 = (const float4*)sWl;
    const float4* sWr4 = (const float4*)sWr;
#pragma unroll 4
    for (int j = 0; j < K; ++j) {
        float4 wl4 = sWl4[j * 12 + q];
        float4 wr4 = sWr4[j * 12 + q];
        float h0 = sH[(ng + 0)  * KP + j];
        float h1 = sH[(ng + 16) * KP + j];
        float h2 = sH[(ng + 32) * KP + j];
        al[0][0] += h0 * wl4.x; al[0][1] += h0 * wl4.y; al[0][2] += h0 * wl4.z; al[0][3] += h0 * wl4.w;
        ar[0][0] += h0 * wr4.x; ar[0][1] += h0 * wr4.y; ar[0][2] += h0 * wr4.z; ar[0][3] += h0 * wr4.w;
        al[1][0] += h1 * wl4.x; al[1][1] += h1 * wl4.y; al[1][2] += h1 * wl4.z; al[1][3] += h1 * wl4.w;
        ar[1][0] += h1 * wr4.x; ar[1][1] += h1 * wr4.y; ar[1][2] += h1 * wr4.z; ar[1][3] += h1 * wr4.w;
        al[2][0] += h2 * wl4.x; al[2][1] += h2 * wl4.y; al[2][2] += h2 * wl4.z; al[2][3] += h2 * wl4.w;
        ar[2][0] += h2 * wr4.x; ar[2][1] += h2 * wr4.y; ar[2][2] += h2 * wr4.z; ar[2][3] += h2 * wr4.w;
    }

    float4 bl4 = ((const float4*)bl)[q];
    float4 br4 = ((const float4*)br)[q];
#pragma unroll
    for (int i = 0; i < 3; ++i) {
        int gn = base + ng + 16 * i;
        if (gn < NNODE) {
            int2 pk = make_int2(f2h(al[i][0] + bl4.x, al[i][1] + bl4.y),
                                f2h(al[i][2] + bl4.z, al[i][3] + bl4.w));
            ((int2*)xlh)[(size_t)gn * 16 + q] = pk;
            float4 orr = make_float4(ar[i][0] + br4.x, ar[i][1] + br4.y,
                                     ar[i][2] + br4.z, ar[i][3] + br4.w);
            ((float4*)xr)[(size_t)gn * 12 + q] = orr;
        }
    }
}

// sum within each 16-lane group (pure-VALU DPP butterfly, broadcast to all 16)
__device__ __forceinline__ float group_sum16(float v) {
#define DPP_ADD(ctrl)                                                          \
    v += __int_as_float(__builtin_amdgcn_update_dpp(                           \
        0, __float_as_int(v), ctrl, 0xf, 0xf, true))
    DPP_ADD(0xB1);    // lane ^ 1
    DPP_ADD(0x4E);    // lane ^ 2
    DPP_ADD(0x141);   // lane ^ 7
    DPP_ADD(0x140);   // lane ^ 15
#undef DPP_ADD
    return v;
}

// fused edge attention + segment softmax (fixed max=0) + aggregation.
// One wave per node; 8 edges per iteration (2 per 16-lane slot) -> two
// independent gathers in flight per lane (latency-bound gather MLP).
__global__ void aggregate_kernel(const __half* __restrict__ xlh, const float* __restrict__ xr,
                                 const int* __restrict__ starts, const int4* __restrict__ edges,
                                 const float* __restrict__ We, const float* __restrict__ att,
                                 const float* __restrict__ bias,
                                 float* __restrict__ hout) {
    int node = (blockIdx.x * blockDim.x + threadIdx.x) >> 6;
    if (node >= NNODE) return;
    const int lane = threadIdx.x & 63;
    const int g = lane >> 4;          // edge slot within chunk (0..3)
    const int r = lane & 15;          // channel quad; active if r < 12
    const bool act = r < 12;
    const int rc = act ? r : 0;

    const float4* We4 = (const float4*)We;
    float4 w0 = We4[4 * rc + 0], w1 = We4[4 * rc + 1],
           w2 = We4[4 * rc + 2], w3 = We4[4 * rc + 3];
    float4 a4 = ((const float4*)att)[rc];
    float aA = act ? a4.x * L2E : 0.f;
    float aB = act ? a4.y * L2E : 0.f;
    float aC = act ? a4.z * L2E : 0.f;
    float aD = act ? a4.w * L2E : 0.f;
    float4 xr4 = ((const float4*)xr)[(size_t)node * 12 + rc];

    int s = starts[node];
    int e_end = starts[node + 1];
    float den = 0.f, ac0 = 0.f, ac1 = 0.f, ac2 = 0.f, ac3 = 0.f;

    for (int j = s; j < e_end; j += 8) {
        int j0 = j + g, j1 = j + 4 + g;
        bool v0 = j0 < e_end, v1 = j1 < e_end;
        int4 edA = edges[v0 ? j0 : j];
        int4 edB = edges[v1 ? j1 : j];
        int2 xiA = ((const int2*)xlh)[(size_t)edA.x * 16 + rc];
        int2 xiB = ((const int2*)xlh)[(size_t)edB.x * 16 + rc];

        float2 eA01 = h2f(edA.y), eA23 = h2f(edA.z);
        float2 eB01 = h2f(edB.y), eB23 = h2f(edB.z);
        float2 xA01 = h2f(xiA.x), xA23 = h2f(xiA.y);
        float2 xB01 = h2f(xiB.x), xB23 = h2f(xiB.y);

        float vA0 = fmaf(w0.w, eA23.y, fmaf(w0.z, eA23.x, fmaf(w0.y, eA01.y, fmaf(w0.x, eA01.x, xA01.x + xr4.x))));
        float vA1 = fmaf(w1.w, eA23.y, fmaf(w1.z, eA23.x, fmaf(w1.y, eA01.y, fmaf(w1.x, eA01.x, xA01.y + xr4.y))));
        float vA2 = fmaf(w2.w, eA23.y, fmaf(w2.z, eA23.x, fmaf(w2.y, eA01.y, fmaf(w2.x, eA01.x, xA23.x + xr4.z))));
        float vA3 = fmaf(w3.w, eA23.y, fmaf(w3.z, eA23.x, fmaf(w3.y, eA01.y, fmaf(w3.x, eA01.x, xA23.y + xr4.w))));
        float vB0 = fmaf(w0.w, eB23.y, fmaf(w0.z, eB23.x, fmaf(w0.y, eB01.y, fmaf(w0.x, eB01.x, xB01.x + xr4.x))));
        float vB1 = fmaf(w1.w, eB23.y, fmaf(w1.z, eB23.x, fmaf(w1.y, eB01.y, fmaf(w1.x, eB01.x, xB01.y + xr4.y))));
        float vB2 = fmaf(w2.w, eB23.y, fmaf(w2.z, eB23.x, fmaf(w2.y, eB01.y, fmaf(w2.x, eB01.x, xB23.x + xr4.z))));
        float vB3 = fmaf(w3.w, eB23.y, fmaf(w3.z, eB23.x, fmaf(w3.y, eB01.y, fmaf(w3.x, eB01.x, xB23.y + xr4.w))));

        float tA, tB;
        tA =           aA * fmaf(SLOPE, fminf(vA0, 0.f), fmaxf(vA0, 0.f));
        tA = fmaf(aB, fmaf(SLOPE, fminf(vA1, 0.f), fmaxf(vA1, 0.f)), tA);
        tA = fmaf(aC, fmaf(SLOPE, fminf(vA2, 0.f), fmaxf(vA2, 0.f)), tA);
        tA = fmaf(aD, fmaf(SLOPE, fminf(vA3, 0.f), fmaxf(vA3, 0.f)), tA);
        tB =           aA * fmaf(SLOPE, fminf(vB0, 0.f), fmaxf(vB0, 0.f));
        tB = fmaf(aB, fmaf(SLOPE, fminf(vB1, 0.f), fmaxf(vB1, 0.f)), tB);
        tB = fmaf(aC, fmaf(SLOPE, fminf(vB2, 0.f), fmaxf(vB2, 0.f)), tB);
        tB = fmaf(aD, fmaf(SLOPE, fminf(vB3, 0.f), fmaxf(vB3, 0.f)), tB);

        tA = group_sum16(tA);
        tB = group_sum16(tB);

        float pA = v0 ? exp2f(tA) : 0.f;
        float pB = v1 ? exp2f(tB) : 0.f;
        den += pA + pB;
        ac0 = fmaf(pB, xB01.x, fmaf(pA, xA01.x, ac0));
        ac1 = fmaf(pB, xB01.y, fmaf(pA, xA01.y, ac1));
        ac2 = fmaf(pB, xB23.x, fmaf(pA, xA23.x, ac2));
        ac3 = fmaf(pB, xB23.y, fmaf(pA, xA23.y, ac3));
    }

    // cross-group reduction: bit4 (xor16) then bit5 (xor32)
    den += __int_as_float(__builtin_amdgcn_ds_swizzle(__float_as_int(den), 0x401F));
    ac0 += __int_as_float(__builtin_amdgcn_ds_swizzle(__float_as_int(ac0), 0x401F));
    ac1 += __int_as_float(__builtin_amdgcn_ds_swizzle(__float_as_int(ac1), 0x401F));
    ac2 += __int_as_float(__builtin_amdgcn_ds_swizzle(__float_as_int(ac2), 0x401F));
    ac3 += __int_as_float(__builtin_amdgcn_ds_swizzle(__float_as_int(ac3), 0x401F));
    den += __shfl_xor(den, 32);
    ac0 += __shfl_xor(ac0, 32);
    ac1 += __shfl_xor(ac1, 32);
    ac2 += __shfl_xor(ac2, 32);
    ac3 += __shfl_xor(ac3, 32);

    if (lane < 16 && act) {
        float inv = 1.f / fmaxf(den, 1e-16f);
        float4 b4 = ((const float4*)bias)[r];
        float4 o = make_float4(fmaxf(fmaf(ac0, inv, b4.x), 0.f),
                               fmaxf(fmaf(ac1, inv, b4.y), 0.f),
                               fmaxf(fmaf(ac2, inv, b4.z), 0.f),
                               fmaxf(fmaf(ac3, inv, b4.w), 0.f));
        ((float4*)hout)[(size_t)node * 12 + r] = o;
    }
}

// ---------------- readout + head ----------------

__global__ void readout_kernel(const float* __restrict__ h, float* __restrict__ g) {
    int wid = (blockIdx.x * blockDim.x + threadIdx.x) >> 6;
    int lane = threadIdx.x & 63;
    int nw = (gridDim.x * blockDim.x) >> 6;
    if (lane < AGG) {
        float acc = 0.f;
        for (int n = wid; n < NNODE; n += nw) acc += h[n * AGG + lane];
        atomicAdd(&g[lane], acc);
    }
}

__global__ void head_kernel(const float* __restrict__ g,
                            const float* __restrict__ fc1w, const float* __restrict__ fc1b,
                            const float* __restrict__ fc2w, const float* __restrict__ fc2b,
                            float* __restrict__ out) {
    __shared__ float sg[AGG];
    __shared__ float s1[FCH];
    __shared__ float s2[NCLS];
    int t = threadIdx.x;
    if (t < AGG) sg[t] = g[t];
    __syncthreads();
    if (t < FCH) {
        float a = fc1b[t];
        for (int j = 0; j < AGG; ++j) a += fc1w[t * AGG + j] * sg[j];
        s1[t] = fmaxf(a, 0.f);
    }
    __syncthreads();
    if (t < NCLS) {
        float a = fc2b[t];
        for (int j = 0; j < FCH; ++j) a += fc2w[t * FCH + j] * s1[j];
        s2[t] = a;
    }
    __syncthreads();
    if (t == 0) {
        float mx = s2[0];
        for (int i = 1; i < NCLS; ++i) mx = fmaxf(mx, s2[i]);
        float ex[NCLS];
        float den = 0.f;
        for (int i = 0; i < NCLS; ++i) { ex[i] = __expf(s2[i] - mx); den += ex[i]; }
        for (int i = 0; i < NCLS; ++i) out[i] = ex[i] / den;
    }
}

// ---------------- launch ----------------

extern "C" void kernel_launch(void* const* d_in, const int* in_sizes, int n_in,
                              void* d_out, int out_size, void* d_ws, size_t ws_size,
                              hipStream_t stream) {
    const float* x  = (const float*)d_in[0];
    const int*   ei = (const int*)d_in[1];
    const float* ea = (const float*)d_in[2];
    const float* Wl[3], *bl[3], *Wr[3], *br[3], *We[3], *att[3], *bb[3];
    for (int l = 0; l < 3; ++l) {
        int base = 3 + l * 7;
        Wl[l]  = (const float*)d_in[base + 0];
        bl[l]  = (const float*)d_in[base + 1];
        Wr[l]  = (const float*)d_in[base + 2];
        br[l]  = (const float*)d_in[base + 3];
        We[l]  = (const float*)d_in[base + 4];
        att[l] = (const float*)d_in[base + 5];
        bb[l]  = (const float*)d_in[base + 6];
    }
    const float* fc1w = (const float*)d_in[24];
    const float* fc1b = (const float*)d_in[25];
    const float* fc2w = (const float*)d_in[26];
    const float* fc2b = (const float*)d_in[27];
    float* outp = (float*)d_out;

    char* ws = (char*)d_ws;
    // region0 (32.0 MB): xlh (12.8 MB) + xr (19.2 MB); ALIASED by bbuf
    // (31.3 MB) whose lifetime (binA->binB) ends before transform writes.
    __half* xlh   = (__half*)ws;
    float*  xr    = (float*)(ws + (size_t)NNODE * 64 * 2);
    int4*   bbuf  = (int4*)ws;
    size_t off = (size_t)NNODE * 64 * 2 + (size_t)NNODE * AGG * 4;
    auto take = [&](size_t bytes) -> void* {
        void* p = ws + off;
        off = (off + bytes + 255) & ~(size_t)255;
        return p;
    };
    float*  h      = (float*)take((size_t)NNODE * AGG * 4);
    int*    deg    = (int*)take((size_t)NNODE * 4);
    int*    starts = (int*)take((size_t)(NNODE + 1) * 4);
    int*    bsum   = (int*)take(1024 * 4);
    int*    bcnt   = (int*)take(NBUCK * 4);
    int4*   edges  = (int4*)take((size_t)NEDGE * 16);
    float*  g      = (float*)take(64 * 4);

    const int NB1 = (NNODE + 255) / 256;   // 391

    // CSR build: binA (staged bins + deg) -> scan -> binB (exact CSR scatter)
    hipMemsetAsync(deg, 0, (size_t)NNODE * 4, stream);
    hipMemsetAsync(bcnt, 0, NBUCK * 4, stream);
    binA_kernel<<<(NEDGE + EPB - 1) / EPB, 256, 0, stream>>>(ei, (const float4*)ea,
                                                             deg, bcnt, bbuf);
    scan1_kernel<<<NB1, 256, 0, stream>>>(deg, starts, bsum);
    scan2_kernel<<<1, 512, 0, stream>>>(bsum, NB1);
    scan3_kernel<<<NB1, 256, 0, stream>>>(starts, bsum);
    binB_kernel<<<NBUCK, 1024, 0, stream>>>(bcnt, bbuf, starts, edges);

    const int TGRID = (NNODE + 47) / 48;
    const int AGRID = (NNODE + 3) / 4;

    transform_tiled<FIN><<<TGRID, 192, 0, stream>>>(x, Wl[0], bl[0], Wr[0], br[0], xlh, xr);
    aggregate_kernel<<<AGRID, 256, 0, stream>>>(xlh, xr, starts, edges,
                                                We[0], att[0], bb[0], h);
    transform_tiled<AGG><<<TGRID, 192, 0, stream>>>(h, Wl[1], bl[1], Wr[1], br[1], xlh, xr);
    aggregate_kernel<<<AGRID, 256, 0, stream>>>(xlh, xr, starts, edges,
                                                We[1], att[1], bb[1], h);
    transform_tiled<AGG><<<TGRID, 192, 0, stream>>>(h, Wl[2], bl[2], Wr[2], br[2], xlh, xr);
    aggregate_kernel<<<AGRID, 256, 0, stream>>>(xlh, xr, starts, edges,
                                                We[2], att[2], bb[2], h);

    hipMemsetAsync(g, 0, 64 * 4, stream);
    readout_kernel<<<256, 256, 0, stream>>>(h, g);
    head_kernel<<<1, 192, 0, stream>>>(g, fc1w, fc1b, fc2w, fc2b, outp);
}

// Round 9
// 450.575 us; speedup vs baseline: 1.1320x; 1.1320x over previous
//
#include <hip/hip_runtime.h>
#include <hip/hip_fp16.h>
#include <math.h>

#define NNODE 100000
#define NEDGE 1600000
#define FIN   128
#define AGG   48
#define FCH   192
#define NCLS  10
#define SLOPE 0.2f
#define L2E   1.44269504088896340736f

#define NBUCK 391     // ceil(NNODE/256) coarse dst-buckets (256 nodes each)
#define BCAP  4992    // bucket capacity: mean 4096, sigma 64 -> +14 sigma
#define EPB   2048    // edges per binA block

// fp16 pack/unpack helpers
__device__ __forceinline__ float2 h2f(int p) {
    union { int i; __half2 h; } u; u.i = p;
    return __half22float2(u.h);
}
__device__ __forceinline__ int f2h(float a, float b) {
    union { __half2 h; int i; } u;
    u.h = __floats2half2_rn(a, b);
    return u.i;
}

// ---------------- CSR build (two-level counting sort, no node histogram) ----

// Pass A, LDS-staged: bin 2048 edges into coarse buckets. NO per-node deg
// atomics (R8 showed 1.6M atomics into 400KB = the ~100us wall). Records
// staged in LDS grouped by bucket, then written out linearly (coalesced runs).
__global__ __launch_bounds__(256) void binA_kernel(const int* __restrict__ ei,
                                                   const float4* __restrict__ ea,
                                                   int* __restrict__ bcnt,
                                                   int4* __restrict__ bbuf) {
    __shared__ int  hist[NBUCK];
    __shared__ int  lofs[NBUCK];     // exclusive scan of hist (block-local)
    __shared__ int  gbase[NBUCK];    // reserved global base within bucket
    __shared__ int  scA[512], scB[512];
    __shared__ int  gidx[EPB];       // per-slot global bbuf index (-1 = drop)
    __shared__ int4 stage[EPB];

    const int t = threadIdx.x;
    const int wgbase = blockIdx.x * EPB;
    const int nvalid = min(EPB, NEDGE - wgbase);

    for (int i = t; i < NBUCK; i += 256) hist[i] = 0;
    __syncthreads();

    int d[8], rank[8];
#pragma unroll
    for (int i = 0; i < 8; ++i) {
        int e = wgbase + i * 256 + t;
        if (e < NEDGE) {
            d[i] = ei[NEDGE + e];
            rank[i] = atomicAdd(&hist[d[i] >> 8], 1);
        } else d[i] = -1;
    }
    __syncthreads();

    // Hillis-Steele inclusive scan of hist (padded to 512), ping-pong A->B
    {
        scA[t] = (t < NBUCK) ? hist[t] : 0;
        scA[t + 256] = (t + 256 < NBUCK) ? hist[t + 256] : 0;
        __syncthreads();
        int* src = scA; int* dst = scB;
#pragma unroll
        for (int o = 1; o < 512; o <<= 1) {
            int i0 = t, i1 = t + 256;
            int v0 = src[i0] + ((i0 >= o) ? src[i0 - o] : 0);
            int v1 = src[i1] + ((i1 >= o) ? src[i1 - o] : 0);
            __syncthreads();
            dst[i0] = v0; dst[i1] = v1;
            __syncthreads();
            int* tmp = src; src = dst; dst = tmp;
        }
        if (t < NBUCK) lofs[t] = src[t] - hist[t];
        if (t + 256 < NBUCK) lofs[t + 256] = src[t + 256] - hist[t + 256];
    }
    // reserve global ranges (one atomic per non-empty (wg,bucket))
    for (int i = t; i < NBUCK; i += 256)
        gbase[i] = hist[i] ? atomicAdd(&bcnt[i], hist[i]) : 0;
    __syncthreads();

    // stage records grouped by bucket
#pragma unroll
    for (int i = 0; i < 8; ++i) {
        int e = wgbase + i * 256 + t;
        if (e < NEDGE) {
            int b = d[i] >> 8;
            int slot = lofs[b] + rank[i];
            int gp = gbase[b] + rank[i];
            float4 v = ea[e];
            stage[slot] = make_int4(ei[e], d[i], f2h(v.x, v.y), f2h(v.z, v.w));
            gidx[slot] = (gp < BCAP) ? (b * BCAP + gp) : -1;
        }
    }
    __syncthreads();

    // linear write-out: consecutive slots = same bucket, consecutive global
    // addresses -> coalesced full-line runs
    for (int i = t; i < nvalid; i += 256) {
        int gi = gidx[i];
        if (gi >= 0) bbuf[gi] = stage[i];
    }
}

// exclusive scan of the 391 bucket totals (single block)
__global__ void bscan_kernel(const int* __restrict__ bcnt, int* __restrict__ bstart,
                             int* __restrict__ starts) {
    __shared__ int s[512];
    int t = threadIdx.x;
    int v = (t < NBUCK) ? bcnt[t] : 0;
    s[t] = v;
    __syncthreads();
    int acc = v;
    for (int o = 1; o < 512; o <<= 1) {
        int x = (t >= o) ? s[t - o] : 0;
        __syncthreads();
        acc += x;
        s[t] = acc;
        __syncthreads();
    }
    if (t < NBUCK) bstart[t] = acc - v;
    if (t == 0) starts[NNODE] = NEDGE;
}

// Pass B: one workgroup (1024 threads) per coarse bucket. Counts its 256
// nodes in LDS (replacing the removed global deg histogram), 256-wide LDS
// scan -> per-node starts (written to global CSR offsets) -> exact-slot
// scatter into the bucket's contiguous span (~64KB, one XCD).
__global__ __launch_bounds__(1024) void binB_kernel(const int* __restrict__ bcnt,
                                                    const int* __restrict__ bstart,
                                                    const int4* __restrict__ bbuf,
                                                    int* __restrict__ starts,
                                                    int4* __restrict__ edges) {
    __shared__ int ncnt[256];
    __shared__ int sc[256];
    __shared__ int lcur[256];
    const int b = blockIdx.x;
    const int t = threadIdx.x;
    if (t < 256) ncnt[t] = 0;
    __syncthreads();
    int cnt = min(bcnt[b], BCAP);
    int base = bstart[b];
    for (int i = t; i < cnt; i += 1024)
        atomicAdd(&ncnt[bbuf[(size_t)b * BCAP + i].y & 255], 1);
    __syncthreads();
    // 256-wide Hillis-Steele scan (all threads hit barriers)
    int v = 0, acc = 0;
    if (t < 256) { v = ncnt[t]; sc[t] = v; }
    __syncthreads();
    acc = v;
    for (int o = 1; o < 256; o <<= 1) {
        int x = 0;
        if (t < 256 && t >= o) x = sc[t - o];
        __syncthreads();
        if (t < 256) { acc += x; sc[t] = acc; }
        __syncthreads();
    }
    if (t < 256) {
        int node = (b << 8) + t;
        int st = base + acc - v;      // exclusive
        lcur[t] = st;
        if (node < NNODE) starts[node] = st;
    }
    __syncthreads();
    for (int i = t; i < cnt; i += 1024) {
        int4 rec = bbuf[(size_t)b * BCAP + i];
        int pos = atomicAdd(&lcur[rec.y & 255], 1);
        edges[pos] = make_int4(rec.x, rec.z, rec.w, 0);
    }
}

// ---------------- per-layer kernels ----------------

// LDS-tiled dual GEMM. xl written packed fp16, row padded to 64 halfs (128B)
// so the aggregate's per-edge gather touches exactly one cache line.
template <int K>
__global__ __launch_bounds__(192) void transform_tiled(
    const float* __restrict__ h,
    const float* __restrict__ Wl, const float* __restrict__ bl,
    const float* __restrict__ Wr, const float* __restrict__ br,
    __half* __restrict__ xlh, float* __restrict__ xr)
{
    constexpr int NT = 48;
    constexpr int KP = K + 1;
    __shared__ float sWl[K * 48];
    __shared__ float sWr[K * 48];
    __shared__ float sH[NT * KP];

    const int t = threadIdx.x;
    const int base = blockIdx.x * NT;

    for (int idx = t; idx < 48 * K; idx += 192) {
        int k = idx / K;
        int j = idx - k * K;
        sWl[j * 48 + k] = Wl[idx];
        sWr[j * 48 + k] = Wr[idx];
    }
    for (int p = t; p < NT * (K / 4); p += 192) {
        int row = p / (K / 4);
        int c4  = p - row * (K / 4);
        int gn  = base + row;
        float4 v = (gn < NNODE) ? ((const float4*)h)[(size_t)gn * (K / 4) + c4]
                                : make_float4(0.f, 0.f, 0.f, 0.f);
        float* d = &sH[row * KP + c4 * 4];
        d[0] = v.x; d[1] = v.y; d[2] = v.z; d[3] = v.w;
    }
    __syncthreads();

    const int q  = t % 12;
    const int ng = t / 12;
    float al[3][4] = {};
    float ar[3][4] = {};

    const float4* sWl4 = (const float4*)sWl;
    const float4* sWr4 = (const float4*)sWr;
#pragma unroll 4
    for (int j = 0; j < K; ++j) {
        float4 wl4 = sWl4[j * 12 + q];
        float4 wr4 = sWr4[j * 12 + q];
        float h0 = sH[(ng + 0)  * KP + j];
        float h1 = sH[(ng + 16) * KP + j];
        float h2 = sH[(ng + 32) * KP + j];
        al[0][0] += h0 * wl4.x; al[0][1] += h0 * wl4.y; al[0][2] += h0 * wl4.z; al[0][3] += h0 * wl4.w;
        ar[0][0] += h0 * wr4.x; ar[0][1] += h0 * wr4.y; ar[0][2] += h0 * wr4.z; ar[0][3] += h0 * wr4.w;
        al[1][0] += h1 * wl4.x; al[1][1] += h1 * wl4.y; al[1][2] += h1 * wl4.z; al[1][3] += h1 * wl4.w;
        ar[1][0] += h1 * wr4.x; ar[1][1] += h1 * wr4.y; ar[1][2] += h1 * wr4.z; ar[1][3] += h1 * wr4.w;
        al[2][0] += h2 * wl4.x; al[2][1] += h2 * wl4.y; al[2][2] += h2 * wl4.z; al[2][3] += h2 * wl4.w;
        ar[2][0] += h2 * wr4.x; ar[2][1] += h2 * wr4.y; ar[2][2] += h2 * wr4.z; ar[2][3] += h2 * wr4.w;
    }

    float4 bl4 = ((const float4*)bl)[q];
    float4 br4 = ((const float4*)br)[q];
#pragma unroll
    for (int i = 0; i < 3; ++i) {
        int gn = base + ng + 16 * i;
        if (gn < NNODE) {
            int2 pk = make_int2(f2h(al[i][0] + bl4.x, al[i][1] + bl4.y),
                                f2h(al[i][2] + bl4.z, al[i][3] + bl4.w));
            ((int2*)xlh)[(size_t)gn * 16 + q] = pk;
            float4 orr = make_float4(ar[i][0] + br4.x, ar[i][1] + br4.y,
                                     ar[i][2] + br4.z, ar[i][3] + br4.w);
            ((float4*)xr)[(size_t)gn * 12 + q] = orr;
        }
    }
}

// sum within each 16-lane group (pure-VALU DPP butterfly, broadcast to all 16)
__device__ __forceinline__ float group_sum16(float v) {
#define DPP_ADD(ctrl)                                                          \
    v += __int_as_float(__builtin_amdgcn_update_dpp(                           \
        0, __float_as_int(v), ctrl, 0xf, 0xf, true))
    DPP_ADD(0xB1);    // lane ^ 1
    DPP_ADD(0x4E);    // lane ^ 2
    DPP_ADD(0x141);   // lane ^ 7
    DPP_ADD(0x140);   // lane ^ 15
#undef DPP_ADD
    return v;
}

// fused edge attention + segment softmax (fixed max=0) + aggregation.
// One wave per node; 8 edges per iteration (2 per 16-lane slot) -> two
// independent gathers in flight per lane (latency-bound gather MLP).
__global__ void aggregate_kernel(const __half* __restrict__ xlh, const float* __restrict__ xr,
                                 const int* __restrict__ starts, const int4* __restrict__ edges,
                                 const float* __restrict__ We, const float* __restrict__ att,
                                 const float* __restrict__ bias,
                                 float* __restrict__ hout) {
    int node = (blockIdx.x * blockDim.x + threadIdx.x) >> 6;
    if (node >= NNODE) return;
    const int lane = threadIdx.x & 63;
    const int g = lane >> 4;          // edge slot within chunk (0..3)
    const int r = lane & 15;          // channel quad; active if r < 12
    const bool act = r < 12;
    const int rc = act ? r : 0;

    const float4* We4 = (const float4*)We;
    float4 w0 = We4[4 * rc + 0], w1 = We4[4 * rc + 1],
           w2 = We4[4 * rc + 2], w3 = We4[4 * rc + 3];
    float4 a4 = ((const float4*)att)[rc];
    float aA = act ? a4.x * L2E : 0.f;
    float aB = act ? a4.y * L2E : 0.f;
    float aC = act ? a4.z * L2E : 0.f;
    float aD = act ? a4.w * L2E : 0.f;
    float4 xr4 = ((const float4*)xr)[(size_t)node * 12 + rc];

    int s = starts[node];
    int e_end = starts[node + 1];
    float den = 0.f, ac0 = 0.f, ac1 = 0.f, ac2 = 0.f, ac3 = 0.f;

    for (int j = s; j < e_end; j += 8) {
        int j0 = j + g, j1 = j + 4 + g;
        bool v0 = j0 < e_end, v1 = j1 < e_end;
        int4 edA = edges[v0 ? j0 : j];
        int4 edB = edges[v1 ? j1 : j];
        int2 xiA = ((const int2*)xlh)[(size_t)edA.x * 16 + rc];
        int2 xiB = ((const int2*)xlh)[(size_t)edB.x * 16 + rc];

        float2 eA01 = h2f(edA.y), eA23 = h2f(edA.z);
        float2 eB01 = h2f(edB.y), eB23 = h2f(edB.z);
        float2 xA01 = h2f(xiA.x), xA23 = h2f(xiA.y);
        float2 xB01 = h2f(xiB.x), xB23 = h2f(xiB.y);

        float vA0 = fmaf(w0.w, eA23.y, fmaf(w0.z, eA23.x, fmaf(w0.y, eA01.y, fmaf(w0.x, eA01.x, xA01.x + xr4.x))));
        float vA1 = fmaf(w1.w, eA23.y, fmaf(w1.z, eA23.x, fmaf(w1.y, eA01.y, fmaf(w1.x, eA01.x, xA01.y + xr4.y))));
        float vA2 = fmaf(w2.w, eA23.y, fmaf(w2.z, eA23.x, fmaf(w2.y, eA01.y, fmaf(w2.x, eA01.x, xA23.x + xr4.z))));
        float vA3 = fmaf(w3.w, eA23.y, fmaf(w3.z, eA23.x, fmaf(w3.y, eA01.y, fmaf(w3.x, eA01.x, xA23.y + xr4.w))));
        float vB0 = fmaf(w0.w, eB23.y, fmaf(w0.z, eB23.x, fmaf(w0.y, eB01.y, fmaf(w0.x, eB01.x, xB01.x + xr4.x))));
        float vB1 = fmaf(w1.w, eB23.y, fmaf(w1.z, eB23.x, fmaf(w1.y, eB01.y, fmaf(w1.x, eB01.x, xB01.y + xr4.y))));
        float vB2 = fmaf(w2.w, eB23.y, fmaf(w2.z, eB23.x, fmaf(w2.y, eB01.y, fmaf(w2.x, eB01.x, xB23.x + xr4.z))));
        float vB3 = fmaf(w3.w, eB23.y, fmaf(w3.z, eB23.x, fmaf(w3.y, eB01.y, fmaf(w3.x, eB01.x, xB23.y + xr4.w))));

        float tA, tB;
        tA =           aA * fmaf(SLOPE, fminf(vA0, 0.f), fmaxf(vA0, 0.f));
        tA = fmaf(aB, fmaf(SLOPE, fminf(vA1, 0.f), fmaxf(vA1, 0.f)), tA);
        tA = fmaf(aC, fmaf(SLOPE, fminf(vA2, 0.f), fmaxf(vA2, 0.f)), tA);
        tA = fmaf(aD, fmaf(SLOPE, fminf(vA3, 0.f), fmaxf(vA3, 0.f)), tA);
        tB =           aA * fmaf(SLOPE, fminf(vB0, 0.f), fmaxf(vB0, 0.f));
        tB = fmaf(aB, fmaf(SLOPE, fminf(vB1, 0.f), fmaxf(vB1, 0.f)), tB);
        tB = fmaf(aC, fmaf(SLOPE, fminf(vB2, 0.f), fmaxf(vB2, 0.f)), tB);
        tB = fmaf(aD, fmaf(SLOPE, fminf(vB3, 0.f), fmaxf(vB3, 0.f)), tB);

        tA = group_sum16(tA);
        tB = group_sum16(tB);

        float pA = v0 ? exp2f(tA) : 0.f;
        float pB = v1 ? exp2f(tB) : 0.f;
        den += pA + pB;
        ac0 = fmaf(pB, xB01.x, fmaf(pA, xA01.x, ac0));
        ac1 = fmaf(pB, xB01.y, fmaf(pA, xA01.y, ac1));
        ac2 = fmaf(pB, xB23.x, fmaf(pA, xA23.x, ac2));
        ac3 = fmaf(pB, xB23.y, fmaf(pA, xA23.y, ac3));
    }

    // cross-group reduction: bit4 (xor16) then bit5 (xor32)
    den += __int_as_float(__builtin_amdgcn_ds_swizzle(__float_as_int(den), 0x401F));
    ac0 += __int_as_float(__builtin_amdgcn_ds_swizzle(__float_as_int(ac0), 0x401F));
    ac1 += __int_as_float(__builtin_amdgcn_ds_swizzle(__float_as_int(ac1), 0x401F));
    ac2 += __int_as_float(__builtin_amdgcn_ds_swizzle(__float_as_int(ac2), 0x401F));
    ac3 += __int_as_float(__builtin_amdgcn_ds_swizzle(__float_as_int(ac3), 0x401F));
    den += __shfl_xor(den, 32);
    ac0 += __shfl_xor(ac0, 32);
    ac1 += __shfl_xor(ac1, 32);
    ac2 += __shfl_xor(ac2, 32);
    ac3 += __shfl_xor(ac3, 32);

    if (lane < 16 && act) {
        float inv = 1.f / fmaxf(den, 1e-16f);
        float4 b4 = ((const float4*)bias)[r];
        float4 o = make_float4(fmaxf(fmaf(ac0, inv, b4.x), 0.f),
                               fmaxf(fmaf(ac1, inv, b4.y), 0.f),
                               fmaxf(fmaf(ac2, inv, b4.z), 0.f),
                               fmaxf(fmaf(ac3, inv, b4.w), 0.f));
        ((float4*)hout)[(size_t)node * 12 + r] = o;
    }
}

// ---------------- readout + head ----------------

__global__ void readout_kernel(const float* __restrict__ h, float* __restrict__ g) {
    int wid = (blockIdx.x * blockDim.x + threadIdx.x) >> 6;
    int lane = threadIdx.x & 63;
    int nw = (gridDim.x * blockDim.x) >> 6;
    if (lane < AGG) {
        float acc = 0.f;
        for (int n = wid; n < NNODE; n += nw) acc += h[n * AGG + lane];
        atomicAdd(&g[lane], acc);
    }
}

__global__ void head_kernel(const float* __restrict__ g,
                            const float* __restrict__ fc1w, const float* __restrict__ fc1b,
                            const float* __restrict__ fc2w, const float* __restrict__ fc2b,
                            float* __restrict__ out) {
    __shared__ float sg[AGG];
    __shared__ float s1[FCH];
    __shared__ float s2[NCLS];
    int t = threadIdx.x;
    if (t < AGG) sg[t] = g[t];
    __syncthreads();
    if (t < FCH) {
        float a = fc1b[t];
        for (int j = 0; j < AGG; ++j) a += fc1w[t * AGG + j] * sg[j];
        s1[t] = fmaxf(a, 0.f);
    }
    __syncthreads();
    if (t < NCLS) {
        float a = fc2b[t];
        for (int j = 0; j < FCH; ++j) a += fc2w[t * FCH + j] * s1[j];
        s2[t] = a;
    }
    __syncthreads();
    if (t == 0) {
        float mx = s2[0];
        for (int i = 1; i < NCLS; ++i) mx = fmaxf(mx, s2[i]);
        float ex[NCLS];
        float den = 0.f;
        for (int i = 0; i < NCLS; ++i) { ex[i] = __expf(s2[i] - mx); den += ex[i]; }
        for (int i = 0; i < NCLS; ++i) out[i] = ex[i] / den;
    }
}

// ---------------- launch ----------------

extern "C" void kernel_launch(void* const* d_in, const int* in_sizes, int n_in,
                              void* d_out, int out_size, void* d_ws, size_t ws_size,
                              hipStream_t stream) {
    const float* x  = (const float*)d_in[0];
    const int*   ei = (const int*)d_in[1];
    const float* ea = (const float*)d_in[2];
    const float* Wl[3], *bl[3], *Wr[3], *br[3], *We[3], *att[3], *bb[3];
    for (int l = 0; l < 3; ++l) {
        int base = 3 + l * 7;
        Wl[l]  = (const float*)d_in[base + 0];
        bl[l]  = (const float*)d_in[base + 1];
        Wr[l]  = (const float*)d_in[base + 2];
        br[l]  = (const float*)d_in[base + 3];
        We[l]  = (const float*)d_in[base + 4];
        att[l] = (const float*)d_in[base + 5];
        bb[l]  = (const float*)d_in[base + 6];
    }
    const float* fc1w = (const float*)d_in[24];
    const float* fc1b = (const float*)d_in[25];
    const float* fc2w = (const float*)d_in[26];
    const float* fc2b = (const float*)d_in[27];
    float* outp = (float*)d_out;

    char* ws = (char*)d_ws;
    // region0 (32.0 MB): xlh (12.8 MB) + xr (19.2 MB); ALIASED by bbuf
    // (31.3 MB) whose lifetime (binA->binB) ends before transform writes.
    __half* xlh   = (__half*)ws;
    float*  xr    = (float*)(ws + (size_t)NNODE * 64 * 2);
    int4*   bbuf  = (int4*)ws;
    size_t off = (size_t)NNODE * 64 * 2 + (size_t)NNODE * AGG * 4;
    auto take = [&](size_t bytes) -> void* {
        void* p = ws + off;
        off = (off + bytes + 255) & ~(size_t)255;
        return p;
    };
    float*  h      = (float*)take((size_t)NNODE * AGG * 4);
    int*    starts = (int*)take((size_t)(NNODE + 1) * 4);
    int*    bcnt   = (int*)take(NBUCK * 4);
    int*    bstart = (int*)take((NBUCK + 1) * 4);
    int4*   edges  = (int4*)take((size_t)NEDGE * 16);
    float*  g      = (float*)take(64 * 4);

    // CSR build: binA (bucket bins) -> bucket scan -> binB (per-node count +
    // starts + exact CSR scatter)
    hipMemsetAsync(bcnt, 0, NBUCK * 4, stream);
    binA_kernel<<<(NEDGE + EPB - 1) / EPB, 256, 0, stream>>>(ei, (const float4*)ea,
                                                             bcnt, bbuf);
    bscan_kernel<<<1, 512, 0, stream>>>(bcnt, bstart, starts);
    binB_kernel<<<NBUCK, 1024, 0, stream>>>(bcnt, bstart, bbuf, starts, edges);

    const int TGRID = (NNODE + 47) / 48;
    const int AGRID = (NNODE + 3) / 4;

    transform_tiled<FIN><<<TGRID, 192, 0, stream>>>(x, Wl[0], bl[0], Wr[0], br[0], xlh, xr);
    aggregate_kernel<<<AGRID, 256, 0, stream>>>(xlh, xr, starts, edges,
                                                We[0], att[0], bb[0], h);
    transform_tiled<AGG><<<TGRID, 192, 0, stream>>>(h, Wl[1], bl[1], Wr[1], br[1], xlh, xr);
    aggregate_kernel<<<AGRID, 256, 0, stream>>>(xlh, xr, starts, edges,
                                                We[1], att[1], bb[1], h);
    transform_tiled<AGG><<<TGRID, 192, 0, stream>>>(h, Wl[2], bl[2], Wr[2], br[2], xlh, xr);
    aggregate_kernel<<<AGRID, 256, 0, stream>>>(xlh, xr, starts, edges,
                                                We[2], att[2], bb[2], h);

    hipMemsetAsync(g, 0, 64 * 4, stream);
    readout_kernel<<<256, 256, 0, stream>>>(h, g);
    head_kernel<<<1, 192, 0, stream>>>(g, fc1w, fc1b, fc2w, fc2b, outp);
}

// Round 10
// 416.536 us; speedup vs baseline: 1.2245x; 1.0817x over previous
//
#include <hip/hip_runtime.h>
#include <hip/hip_fp16.h>
#include <math.h>

#define NNODE 100000
#define NEDGE 1600000
#define FIN   128
#define AGG   48
#define FCH   192
#define NCLS  10
#define SLOPE 0.2f
#define L2E   1.44269504088896340736f

#define NBUCK 391     // ceil(NNODE/256) coarse dst-buckets (256 nodes each)
#define BCAP  4992    // bucket capacity: mean 4096, sigma 64 -> +14 sigma
#define EPB   2048    // edges per binA block

// fp16 pack/unpack helpers
__device__ __forceinline__ float2 h2f(int p) {
    union { int i; __half2 h; } u; u.i = p;
    return __half22float2(u.h);
}
__device__ __forceinline__ int f2h(float a, float b) {
    union { __half2 h; int i; } u;
    u.h = __floats2half2_rn(a, b);
    return u.i;
}

// ---------------- CSR build (two-level counting sort, no node histogram) ----

// Pass A, LDS-staged: bin 2048 edges into coarse buckets; records staged in
// LDS grouped by bucket, written out linearly (coalesced runs). No per-node
// atomics (R8: 1.6M atomics into 400KB was a ~100us wall).
__global__ __launch_bounds__(256) void binA_kernel(const int* __restrict__ ei,
                                                   const float4* __restrict__ ea,
                                                   int* __restrict__ bcnt,
                                                   int4* __restrict__ bbuf) {
    __shared__ int  hist[NBUCK];
    __shared__ int  lofs[NBUCK];     // exclusive scan of hist (block-local)
    __shared__ int  gbase[NBUCK];    // reserved global base within bucket
    __shared__ int  scA[512], scB[512];
    __shared__ int  gidx[EPB];       // per-slot global bbuf index (-1 = drop)
    __shared__ int4 stage[EPB];

    const int t = threadIdx.x;
    const int wgbase = blockIdx.x * EPB;
    const int nvalid = min(EPB, NEDGE - wgbase);

    for (int i = t; i < NBUCK; i += 256) hist[i] = 0;
    __syncthreads();

    int d[8], rank[8];
#pragma unroll
    for (int i = 0; i < 8; ++i) {
        int e = wgbase + i * 256 + t;
        if (e < NEDGE) {
            d[i] = ei[NEDGE + e];
            rank[i] = atomicAdd(&hist[d[i] >> 8], 1);
        } else d[i] = -1;
    }
    __syncthreads();

    // Hillis-Steele inclusive scan of hist (padded to 512), ping-pong A->B
    {
        scA[t] = (t < NBUCK) ? hist[t] : 0;
        scA[t + 256] = (t + 256 < NBUCK) ? hist[t + 256] : 0;
        __syncthreads();
        int* src = scA; int* dst = scB;
#pragma unroll
        for (int o = 1; o < 512; o <<= 1) {
            int i0 = t, i1 = t + 256;
            int v0 = src[i0] + ((i0 >= o) ? src[i0 - o] : 0);
            int v1 = src[i1] + ((i1 >= o) ? src[i1 - o] : 0);
            __syncthreads();
            dst[i0] = v0; dst[i1] = v1;
            __syncthreads();
            int* tmp = src; src = dst; dst = tmp;
        }
        if (t < NBUCK) lofs[t] = src[t] - hist[t];
        if (t + 256 < NBUCK) lofs[t + 256] = src[t + 256] - hist[t + 256];
    }
    for (int i = t; i < NBUCK; i += 256)
        gbase[i] = hist[i] ? atomicAdd(&bcnt[i], hist[i]) : 0;
    __syncthreads();

#pragma unroll
    for (int i = 0; i < 8; ++i) {
        int e = wgbase + i * 256 + t;
        if (e < NEDGE) {
            int b = d[i] >> 8;
            int slot = lofs[b] + rank[i];
            int gp = gbase[b] + rank[i];
            float4 v = ea[e];
            stage[slot] = make_int4(ei[e], d[i], f2h(v.x, v.y), f2h(v.z, v.w));
            gidx[slot] = (gp < BCAP) ? (b * BCAP + gp) : -1;
        }
    }
    __syncthreads();

    for (int i = t; i < nvalid; i += 256) {
        int gi = gidx[i];
        if (gi >= 0) bbuf[gi] = stage[i];
    }
}

// exclusive scan of the 391 bucket totals (single block)
__global__ void bscan_kernel(const int* __restrict__ bcnt, int* __restrict__ bstart,
                             int* __restrict__ starts) {
    __shared__ int s[512];
    int t = threadIdx.x;
    int v = (t < NBUCK) ? bcnt[t] : 0;
    s[t] = v;
    __syncthreads();
    int acc = v;
    for (int o = 1; o < 512; o <<= 1) {
        int x = (t >= o) ? s[t - o] : 0;
        __syncthreads();
        acc += x;
        s[t] = acc;
        __syncthreads();
    }
    if (t < NBUCK) bstart[t] = acc - v;
    if (t == 0) starts[NNODE] = NEDGE;
}

// Pass B: one workgroup (1024 threads) per coarse bucket; per-node LDS count
// + scan -> starts[]; exact-slot scatter into the bucket's contiguous span.
__global__ __launch_bounds__(1024) void binB_kernel(const int* __restrict__ bcnt,
                                                    const int* __restrict__ bstart,
                                                    const int4* __restrict__ bbuf,
                                                    int* __restrict__ starts,
                                                    int4* __restrict__ edges) {
    __shared__ int ncnt[256];
    __shared__ int sc[256];
    __shared__ int lcur[256];
    const int b = blockIdx.x;
    const int t = threadIdx.x;
    if (t < 256) ncnt[t] = 0;
    __syncthreads();
    int cnt = min(bcnt[b], BCAP);
    int base = bstart[b];
    for (int i = t; i < cnt; i += 1024)
        atomicAdd(&ncnt[bbuf[(size_t)b * BCAP + i].y & 255], 1);
    __syncthreads();
    int v = 0, acc = 0;
    if (t < 256) { v = ncnt[t]; sc[t] = v; }
    __syncthreads();
    acc = v;
    for (int o = 1; o < 256; o <<= 1) {
        int x = 0;
        if (t < 256 && t >= o) x = sc[t - o];
        __syncthreads();
        if (t < 256) { acc += x; sc[t] = acc; }
        __syncthreads();
    }
    if (t < 256) {
        int node = (b << 8) + t;
        int st = base + acc - v;      // exclusive
        lcur[t] = st;
        if (node < NNODE) starts[node] = st;
    }
    __syncthreads();
    for (int i = t; i < cnt; i += 1024) {
        int4 rec = bbuf[(size_t)b * BCAP + i];
        int pos = atomicAdd(&lcur[rec.y & 255], 1);
        edges[pos] = make_int4(rec.x, rec.z, rec.w, 0);
    }
}

// ---------------- per-layer kernels ----------------

// LDS-tiled dual GEMM, conflict-free layouts (R9: 13.2M bank conflicts from
// stride-48-word W staging (32-way) and 4-word-stride sH stores (8-way)).
//   sW: staged via float4 global reads over j-quads with consecutive lanes =
//       consecutive k -> consecutive-word LDS writes (conflict-free);
//       K-tiled at KT to halve LDS (50KB total -> 3 blocks/CU at K=128).
//   sH: KP=K+4 (KP%4==0) -> float4 stage writes conflict-free; compute reads
//       hit banks (4*ng+j)%32, 6 distinct per wave, broadcast across q.
template <int K, int KT>
__global__ __launch_bounds__(192) void transform_tiled(
    const float* __restrict__ h,
    const float* __restrict__ Wl, const float* __restrict__ bl,
    const float* __restrict__ Wr, const float* __restrict__ br,
    __half* __restrict__ xlh, float* __restrict__ xr)
{
    constexpr int NT = 48;
    constexpr int KP = K + 4;
    __shared__ float sW[2][KT * 48];     // [m][j*48+k] = W^T tile
    __shared__ float sH[NT * KP];

    const int t = threadIdx.x;
    const int base = blockIdx.x * NT;

    // stage H (float4 reads, float4 conflict-free LDS writes)
    for (int p = t; p < NT * (K / 4); p += 192) {
        int row = p / (K / 4);
        int c4  = p - row * (K / 4);
        int gn  = base + row;
        float4 v = (gn < NNODE) ? ((const float4*)h)[(size_t)gn * (K / 4) + c4]
                                : make_float4(0.f, 0.f, 0.f, 0.f);
        ((float4*)(sH + row * KP))[c4] = v;
    }

    const int q  = t % 12;
    const int ng = t / 12;
    float al[3][4] = {};
    float ar[3][4] = {};

    const float4* Wl4 = (const float4*)Wl;
    const float4* Wr4 = (const float4*)Wr;

    for (int j0 = 0; j0 < K; j0 += KT) {
        __syncthreads();   // (iter 0: none reading) protect sW from prev tile
        // stage W^T tile: lane reads quad of j for one k (strided global,
        // L2-resident 24KB); writes consecutive k -> conflict-free
        for (int p = t; p < 48 * (KT / 4); p += 192) {
            int k  = p % 48;
            int jq = p / 48;
            float4 wl = Wl4[(size_t)k * (K / 4) + (j0 / 4) + jq];
            float4 wr = Wr4[(size_t)k * (K / 4) + (j0 / 4) + jq];
            int j = jq * 4;
            sW[0][(j + 0) * 48 + k] = wl.x; sW[0][(j + 1) * 48 + k] = wl.y;
            sW[0][(j + 2) * 48 + k] = wl.z; sW[0][(j + 3) * 48 + k] = wl.w;
            sW[1][(j + 0) * 48 + k] = wr.x; sW[1][(j + 1) * 48 + k] = wr.y;
            sW[1][(j + 2) * 48 + k] = wr.z; sW[1][(j + 3) * 48 + k] = wr.w;
        }
        __syncthreads();

        const float4* sWl4 = (const float4*)sW[0];
        const float4* sWr4 = (const float4*)sW[1];
        const float* sHj = sH + j0;
#pragma unroll 4
        for (int j = 0; j < KT; ++j) {
            float4 wl4 = sWl4[j * 12 + q];
            float4 wr4 = sWr4[j * 12 + q];
            float h0 = sHj[(ng + 0)  * KP + j];
            float h1 = sHj[(ng + 16) * KP + j];
            float h2 = sHj[(ng + 32) * KP + j];
            al[0][0] += h0 * wl4.x; al[0][1] += h0 * wl4.y; al[0][2] += h0 * wl4.z; al[0][3] += h0 * wl4.w;
            ar[0][0] += h0 * wr4.x; ar[0][1] += h0 * wr4.y; ar[0][2] += h0 * wr4.z; ar[0][3] += h0 * wr4.w;
            al[1][0] += h1 * wl4.x; al[1][1] += h1 * wl4.y; al[1][2] += h1 * wl4.z; al[1][3] += h1 * wl4.w;
            ar[1][0] += h1 * wr4.x; ar[1][1] += h1 * wr4.y; ar[1][2] += h1 * wr4.z; ar[1][3] += h1 * wr4.w;
            al[2][0] += h2 * wl4.x; al[2][1] += h2 * wl4.y; al[2][2] += h2 * wl4.z; al[2][3] += h2 * wl4.w;
            ar[2][0] += h2 * wr4.x; ar[2][1] += h2 * wr4.y; ar[2][2] += h2 * wr4.z; ar[2][3] += h2 * wr4.w;
        }
    }

    float4 bl4 = ((const float4*)bl)[q];
    float4 br4 = ((const float4*)br)[q];
#pragma unroll
    for (int i = 0; i < 3; ++i) {
        int gn = base + ng + 16 * i;
        if (gn < NNODE) {
            int2 pk = make_int2(f2h(al[i][0] + bl4.x, al[i][1] + bl4.y),
                                f2h(al[i][2] + bl4.z, al[i][3] + bl4.w));
            ((int2*)xlh)[(size_t)gn * 16 + q] = pk;
            float4 orr = make_float4(ar[i][0] + br4.x, ar[i][1] + br4.y,
                                     ar[i][2] + br4.z, ar[i][3] + br4.w);
            ((float4*)xr)[(size_t)gn * 12 + q] = orr;
        }
    }
}

// sum within each 16-lane group (pure-VALU DPP butterfly, broadcast to all 16)
__device__ __forceinline__ float group_sum16(float v) {
#define DPP_ADD(ctrl)                                                          \
    v += __int_as_float(__builtin_amdgcn_update_dpp(                           \
        0, __float_as_int(v), ctrl, 0xf, 0xf, true))
    DPP_ADD(0xB1);    // lane ^ 1
    DPP_ADD(0x4E);    // lane ^ 2
    DPP_ADD(0x141);   // lane ^ 7
    DPP_ADD(0x140);   // lane ^ 15
#undef DPP_ADD
    return v;
}

// fused edge attention + segment softmax (fixed max=0) + aggregation.
// One wave per node; 8 edges per iteration (2 per 16-lane slot) -> two
// independent gathers in flight per lane (latency-bound gather MLP).
__global__ void aggregate_kernel(const __half* __restrict__ xlh, const float* __restrict__ xr,
                                 const int* __restrict__ starts, const int4* __restrict__ edges,
                                 const float* __restrict__ We, const float* __restrict__ att,
                                 const float* __restrict__ bias,
                                 float* __restrict__ hout) {
    int node = (blockIdx.x * blockDim.x + threadIdx.x) >> 6;
    if (node >= NNODE) return;
    const int lane = threadIdx.x & 63;
    const int g = lane >> 4;          // edge slot within chunk (0..3)
    const int r = lane & 15;          // channel quad; active if r < 12
    const bool act = r < 12;
    const int rc = act ? r : 0;

    const float4* We4 = (const float4*)We;
    float4 w0 = We4[4 * rc + 0], w1 = We4[4 * rc + 1],
           w2 = We4[4 * rc + 2], w3 = We4[4 * rc + 3];
    float4 a4 = ((const float4*)att)[rc];
    float aA = act ? a4.x * L2E : 0.f;
    float aB = act ? a4.y * L2E : 0.f;
    float aC = act ? a4.z * L2E : 0.f;
    float aD = act ? a4.w * L2E : 0.f;
    float4 xr4 = ((const float4*)xr)[(size_t)node * 12 + rc];

    int s = starts[node];
    int e_end = starts[node + 1];
    float den = 0.f, ac0 = 0.f, ac1 = 0.f, ac2 = 0.f, ac3 = 0.f;

    for (int j = s; j < e_end; j += 8) {
        int j0 = j + g, j1 = j + 4 + g;
        bool v0 = j0 < e_end, v1 = j1 < e_end;
        int4 edA = edges[v0 ? j0 : j];
        int4 edB = edges[v1 ? j1 : j];
        int2 xiA = ((const int2*)xlh)[(size_t)edA.x * 16 + rc];
        int2 xiB = ((const int2*)xlh)[(size_t)edB.x * 16 + rc];

        float2 eA01 = h2f(edA.y), eA23 = h2f(edA.z);
        float2 eB01 = h2f(edB.y), eB23 = h2f(edB.z);
        float2 xA01 = h2f(xiA.x), xA23 = h2f(xiA.y);
        float2 xB01 = h2f(xiB.x), xB23 = h2f(xiB.y);

        float vA0 = fmaf(w0.w, eA23.y, fmaf(w0.z, eA23.x, fmaf(w0.y, eA01.y, fmaf(w0.x, eA01.x, xA01.x + xr4.x))));
        float vA1 = fmaf(w1.w, eA23.y, fmaf(w1.z, eA23.x, fmaf(w1.y, eA01.y, fmaf(w1.x, eA01.x, xA01.y + xr4.y))));
        float vA2 = fmaf(w2.w, eA23.y, fmaf(w2.z, eA23.x, fmaf(w2.y, eA01.y, fmaf(w2.x, eA01.x, xA23.x + xr4.z))));
        float vA3 = fmaf(w3.w, eA23.y, fmaf(w3.z, eA23.x, fmaf(w3.y, eA01.y, fmaf(w3.x, eA01.x, xA23.y + xr4.w))));
        float vB0 = fmaf(w0.w, eB23.y, fmaf(w0.z, eB23.x, fmaf(w0.y, eB01.y, fmaf(w0.x, eB01.x, xB01.x + xr4.x))));
        float vB1 = fmaf(w1.w, eB23.y, fmaf(w1.z, eB23.x, fmaf(w1.y, eB01.y, fmaf(w1.x, eB01.x, xB01.y + xr4.y))));
        float vB2 = fmaf(w2.w, eB23.y, fmaf(w2.z, eB23.x, fmaf(w2.y, eB01.y, fmaf(w2.x, eB01.x, xB23.x + xr4.z))));
        float vB3 = fmaf(w3.w, eB23.y, fmaf(w3.z, eB23.x, fmaf(w3.y, eB01.y, fmaf(w3.x, eB01.x, xB23.y + xr4.w))));

        float tA, tB;
        tA =           aA * fmaf(SLOPE, fminf(vA0, 0.f), fmaxf(vA0, 0.f));
        tA = fmaf(aB, fmaf(SLOPE, fminf(vA1, 0.f), fmaxf(vA1, 0.f)), tA);
        tA = fmaf(aC, fmaf(SLOPE, fminf(vA2, 0.f), fmaxf(vA2, 0.f)), tA);
        tA = fmaf(aD, fmaf(SLOPE, fminf(vA3, 0.f), fmaxf(vA3, 0.f)), tA);
        tB =           aA * fmaf(SLOPE, fminf(vB0, 0.f), fmaxf(vB0, 0.f));
        tB = fmaf(aB, fmaf(SLOPE, fminf(vB1, 0.f), fmaxf(vB1, 0.f)), tB);
        tB = fmaf(aC, fmaf(SLOPE, fminf(vB2, 0.f), fmaxf(vB2, 0.f)), tB);
        tB = fmaf(aD, fmaf(SLOPE, fminf(vB3, 0.f), fmaxf(vB3, 0.f)), tB);

        tA = group_sum16(tA);
        tB = group_sum16(tB);

        float pA = v0 ? exp2f(tA) : 0.f;
        float pB = v1 ? exp2f(tB) : 0.f;
        den += pA + pB;
        ac0 = fmaf(pB, xB01.x, fmaf(pA, xA01.x, ac0));
        ac1 = fmaf(pB, xB01.y, fmaf(pA, xA01.y, ac1));
        ac2 = fmaf(pB, xB23.x, fmaf(pA, xA23.x, ac2));
        ac3 = fmaf(pB, xB23.y, fmaf(pA, xA23.y, ac3));
    }

    // cross-group reduction: bit4 (xor16) then bit5 (xor32)
    den += __int_as_float(__builtin_amdgcn_ds_swizzle(__float_as_int(den), 0x401F));
    ac0 += __int_as_float(__builtin_amdgcn_ds_swizzle(__float_as_int(ac0), 0x401F));
    ac1 += __int_as_float(__builtin_amdgcn_ds_swizzle(__float_as_int(ac1), 0x401F));
    ac2 += __int_as_float(__builtin_amdgcn_ds_swizzle(__float_as_int(ac2), 0x401F));
    ac3 += __int_as_float(__builtin_amdgcn_ds_swizzle(__float_as_int(ac3), 0x401F));
    den += __shfl_xor(den, 32);
    ac0 += __shfl_xor(ac0, 32);
    ac1 += __shfl_xor(ac1, 32);
    ac2 += __shfl_xor(ac2, 32);
    ac3 += __shfl_xor(ac3, 32);

    if (lane < 16 && act) {
        float inv = 1.f / fmaxf(den, 1e-16f);
        float4 b4 = ((const float4*)bias)[r];
        float4 o = make_float4(fmaxf(fmaf(ac0, inv, b4.x), 0.f),
                               fmaxf(fmaf(ac1, inv, b4.y), 0.f),
                               fmaxf(fmaf(ac2, inv, b4.z), 0.f),
                               fmaxf(fmaf(ac3, inv, b4.w), 0.f));
        ((float4*)hout)[(size_t)node * 12 + r] = o;
    }
}

// ---------------- readout + head ----------------

__global__ void readout_kernel(const float* __restrict__ h, float* __restrict__ g) {
    int wid = (blockIdx.x * blockDim.x + threadIdx.x) >> 6;
    int lane = threadIdx.x & 63;
    int nw = (gridDim.x * blockDim.x) >> 6;
    if (lane < AGG) {
        float acc = 0.f;
        for (int n = wid; n < NNODE; n += nw) acc += h[n * AGG + lane];
        atomicAdd(&g[lane], acc);
    }
}

__global__ void head_kernel(const float* __restrict__ g,
                            const float* __restrict__ fc1w, const float* __restrict__ fc1b,
                            const float* __restrict__ fc2w, const float* __restrict__ fc2b,
                            float* __restrict__ out) {
    __shared__ float sg[AGG];
    __shared__ float s1[FCH];
    __shared__ float s2[NCLS];
    int t = threadIdx.x;
    if (t < AGG) sg[t] = g[t];
    __syncthreads();
    if (t < FCH) {
        float a = fc1b[t];
        for (int j = 0; j < AGG; ++j) a += fc1w[t * AGG + j] * sg[j];
        s1[t] = fmaxf(a, 0.f);
    }
    __syncthreads();
    if (t < NCLS) {
        float a = fc2b[t];
        for (int j = 0; j < FCH; ++j) a += fc2w[t * FCH + j] * s1[j];
        s2[t] = a;
    }
    __syncthreads();
    if (t == 0) {
        float mx = s2[0];
        for (int i = 1; i < NCLS; ++i) mx = fmaxf(mx, s2[i]);
        float ex[NCLS];
        float den = 0.f;
        for (int i = 0; i < NCLS; ++i) { ex[i] = __expf(s2[i] - mx); den += ex[i]; }
        for (int i = 0; i < NCLS; ++i) out[i] = ex[i] / den;
    }
}

// ---------------- launch ----------------

extern "C" void kernel_launch(void* const* d_in, const int* in_sizes, int n_in,
                              void* d_out, int out_size, void* d_ws, size_t ws_size,
                              hipStream_t stream) {
    const float* x  = (const float*)d_in[0];
    const int*   ei = (const int*)d_in[1];
    const float* ea = (const float*)d_in[2];
    const float* Wl[3], *bl[3], *Wr[3], *br[3], *We[3], *att[3], *bb[3];
    for (int l = 0; l < 3; ++l) {
        int base = 3 + l * 7;
        Wl[l]  = (const float*)d_in[base + 0];
        bl[l]  = (const float*)d_in[base + 1];
        Wr[l]  = (const float*)d_in[base + 2];
        br[l]  = (const float*)d_in[base + 3];
        We[l]  = (const float*)d_in[base + 4];
        att[l] = (const float*)d_in[base + 5];
        bb[l]  = (const float*)d_in[base + 6];
    }
    const float* fc1w = (const float*)d_in[24];
    const float* fc1b = (const float*)d_in[25];
    const float* fc2w = (const float*)d_in[26];
    const float* fc2b = (const float*)d_in[27];
    float* outp = (float*)d_out;

    char* ws = (char*)d_ws;
    // region0 (32.0 MB): xlh (12.8 MB) + xr (19.2 MB); ALIASED by bbuf
    // (31.3 MB) whose lifetime (binA->binB) ends before transform writes.
    __half* xlh   = (__half*)ws;
    float*  xr    = (float*)(ws + (size_t)NNODE * 64 * 2);
    int4*   bbuf  = (int4*)ws;
    size_t off = (size_t)NNODE * 64 * 2 + (size_t)NNODE * AGG * 4;
    auto take = [&](size_t bytes) -> void* {
        void* p = ws + off;
        off = (off + bytes + 255) & ~(size_t)255;
        return p;
    };
    float*  h      = (float*)take((size_t)NNODE * AGG * 4);
    int*    starts = (int*)take((size_t)(NNODE + 1) * 4);
    int*    bcnt   = (int*)take(NBUCK * 4);
    int*    bstart = (int*)take((NBUCK + 1) * 4);
    int4*   edges  = (int4*)take((size_t)NEDGE * 16);
    float*  g      = (float*)take(64 * 4);

    // CSR build: binA (bucket bins) -> bucket scan -> binB (per-node count +
    // starts + exact CSR scatter)
    hipMemsetAsync(bcnt, 0, NBUCK * 4, stream);
    binA_kernel<<<(NEDGE + EPB - 1) / EPB, 256, 0, stream>>>(ei, (const float4*)ea,
                                                             bcnt, bbuf);
    bscan_kernel<<<1, 512, 0, stream>>>(bcnt, bstart, starts);
    binB_kernel<<<NBUCK, 1024, 0, stream>>>(bcnt, bstart, bbuf, starts, edges);

    const int TGRID = (NNODE + 47) / 48;
    const int AGRID = (NNODE + 3) / 4;

    transform_tiled<FIN, 64><<<TGRID, 192, 0, stream>>>(x, Wl[0], bl[0], Wr[0], br[0], xlh, xr);
    aggregate_kernel<<<AGRID, 256, 0, stream>>>(xlh, xr, starts, edges,
                                                We[0], att[0], bb[0], h);
    transform_tiled<AGG, 48><<<TGRID, 192, 0, stream>>>(h, Wl[1], bl[1], Wr[1], br[1], xlh, xr);
    aggregate_kernel<<<AGRID, 256, 0, stream>>>(xlh, xr, starts, edges,
                                                We[1], att[1], bb[1], h);
    transform_tiled<AGG, 48><<<TGRID, 192, 0, stream>>>(h, Wl[2], bl[2], Wr[2], br[2], xlh, xr);
    aggregate_kernel<<<AGRID, 256, 0, stream>>>(xlh, xr, starts, edges,
                                                We[2], att[2], bb[2], h);

    hipMemsetAsync(g, 0, 64 * 4, stream);
    readout_kernel<<<256, 256, 0, stream>>>(h, g);
    head_kernel<<<1, 192, 0, stream>>>(g, fc1w, fc1b, fc2w, fc2b, outp);
}